// Round 1
// baseline (631.163 us; speedup 1.0000x reference)
//
#include <hip/hip_runtime.h>
#include <hip/hip_bf16.h>

#define H 1024
#define SEQ 4096
#define BQ 64   // Kq
#define NB 16   // batch

// ---------------------------------------------------------------------------
// Generic small GEMM: C[1024 x 1024] = (A (+A2)) @ B * scale + bias
// BNK true:  B operand indexed B[n*H + k]   (i.e. X @ W^T, W row-major)
// BNK false: B operand indexed B[k*H + n]   (i.e. X @ W)
// ---------------------------------------------------------------------------
template<bool BNK, bool HAS_A2>
__global__ __launch_bounds__(256)
void gemm_small(const float* __restrict__ A, const float* __restrict__ A2,
                const float* __restrict__ Bm, const float* __restrict__ bias,
                float* __restrict__ C, float scale)
{
    __shared__ float As[32][68];
    __shared__ float Bs[32][68];
    const int m0 = blockIdx.x * 64;
    const int n0 = blockIdx.y * 64;
    const int t  = threadIdx.x;
    const int tn = t & 15;   // 16 -> n in steps of 4
    const int tm = t >> 4;   // 16 -> m in steps of 4
    float acc[4][4] = {};

    for (int k0 = 0; k0 < H; k0 += 32) {
        {   // stage A: 64 rows x 32 k  ->  As[k][m]
            int kk = t & 31;
            int mb = (t >> 5) * 8;
            #pragma unroll
            for (int r = 0; r < 8; ++r) {
                int m = mb + r;
                float v = A[(size_t)(m0 + m) * H + k0 + kk];
                if (HAS_A2) v += A2[(size_t)(m0 + m) * H + k0 + kk];
                As[kk][m] = v;
            }
        }
        if (BNK) { // Bs[k][n] = B[(n0+n)*H + k0+k]
            int kk = t & 31;
            int nb = (t >> 5) * 8;
            #pragma unroll
            for (int r = 0; r < 8; ++r)
                Bs[kk][nb + r] = Bm[(size_t)(n0 + nb + r) * H + k0 + kk];
        } else {   // Bs[k][n] = B[(k0+k)*H + n0+n]
            int n  = t & 63;
            int kb = (t >> 6) * 8;
            #pragma unroll
            for (int r = 0; r < 8; ++r)
                Bs[kb + r][n] = Bm[(size_t)(k0 + kb + r) * H + n0 + n];
        }
        __syncthreads();
        #pragma unroll 8
        for (int kk = 0; kk < 32; ++kk) {
            float4 a4 = *reinterpret_cast<const float4*>(&As[kk][tm * 4]);
            float4 b4 = *reinterpret_cast<const float4*>(&Bs[kk][tn * 4]);
            float av[4] = {a4.x, a4.y, a4.z, a4.w};
            float bv2[4] = {b4.x, b4.y, b4.z, b4.w};
            #pragma unroll
            for (int i = 0; i < 4; ++i)
                #pragma unroll
                for (int j = 0; j < 4; ++j)
                    acc[i][j] += av[i] * bv2[j];
        }
        __syncthreads();
    }

    #pragma unroll
    for (int i = 0; i < 4; ++i) {
        int m = m0 + tm * 4 + i;
        float4 o;
        float* po = &o.x;
        #pragma unroll
        for (int j = 0; j < 4; ++j) {
            float v = acc[i][j] * scale;
            if (bias) v += bias[n0 + tn * 4 + j];
            po[j] = v;
        }
        *reinterpret_cast<float4*>(&C[(size_t)m * H + n0 + tn * 4]) = o;
    }
}

// ---------------------------------------------------------------------------
// c[b,qi] = scale * dot(q[b,qi,:], bk)
// ---------------------------------------------------------------------------
__global__ __launch_bounds__(256)
void cvec_kernel(const float* __restrict__ q, const float* __restrict__ bk,
                 float* __restrict__ cvec, float scale)
{
    int r = blockIdx.x * 4 + (threadIdx.x >> 6);
    int l = threadIdx.x & 63;
    float s = 0.f;
    #pragma unroll
    for (int i = 0; i < 16; ++i)
        s += q[(size_t)r * H + l + 64 * i] * bk[l + 64 * i];
    #pragma unroll
    for (int off = 32; off; off >>= 1)
        s += __shfl_down(s, off);
    if (l == 0) cvec[r] = s * scale;
}

// ---------------------------------------------------------------------------
// scores[b, s, qi] = sum_h keys[b,s,h] * N[b,qi,h] + c[b,qi]
// block: 128 s-rows x 64 qi, grid (32, B)
// ---------------------------------------------------------------------------
__global__ __launch_bounds__(256)
void scores_kernel(const float* __restrict__ keys, const float* __restrict__ Nw,
                   const float* __restrict__ cvec, float* __restrict__ scores)
{
    __shared__ float As[32][132]; // keys  [k][s], 128 s
    __shared__ float Bs[32][68];  // N     [k][qi]
    const int b  = blockIdx.y;
    const int s0 = blockIdx.x * 128;
    const int t  = threadIdx.x;
    const int tn = t & 15;  // qi*4
    const int tm = t >> 4;  // s*8
    const float* kb = keys + (size_t)b * SEQ * H;
    const float* nb = Nw + (size_t)b * BQ * H;
    float acc[8][4] = {};

    for (int k0 = 0; k0 < H; k0 += 32) {
        {   // keys tile 128x32 -> As[k][s]
            int kf = t & 7;
            int sb = t >> 3;
            #pragma unroll
            for (int p = 0; p < 4; ++p) {
                int srow = sb + p * 32;
                float4 v = *reinterpret_cast<const float4*>(
                    &kb[(size_t)(s0 + srow) * H + k0 + kf * 4]);
                As[kf * 4 + 0][srow] = v.x;
                As[kf * 4 + 1][srow] = v.y;
                As[kf * 4 + 2][srow] = v.z;
                As[kf * 4 + 3][srow] = v.w;
            }
        }
        {   // N tile 64x32 -> Bs[k][qi]
            int kk = t & 31;
            int qb = (t >> 5) * 8;
            #pragma unroll
            for (int r = 0; r < 8; ++r)
                Bs[kk][qb + r] = nb[(size_t)(qb + r) * H + k0 + kk];
        }
        __syncthreads();
        #pragma unroll 8
        for (int kk = 0; kk < 32; ++kk) {
            float4 b4 = *reinterpret_cast<const float4*>(&Bs[kk][tn * 4]);
            float a[8];
            *reinterpret_cast<float4*>(&a[0]) =
                *reinterpret_cast<const float4*>(&As[kk][tm * 8]);
            *reinterpret_cast<float4*>(&a[4]) =
                *reinterpret_cast<const float4*>(&As[kk][tm * 8 + 4]);
            float bv2[4] = {b4.x, b4.y, b4.z, b4.w};
            #pragma unroll
            for (int i = 0; i < 8; ++i)
                #pragma unroll
                for (int j = 0; j < 4; ++j)
                    acc[i][j] += a[i] * bv2[j];
        }
        __syncthreads();
    }

    float c[4];
    #pragma unroll
    for (int j = 0; j < 4; ++j) c[j] = cvec[b * BQ + tn * 4 + j];
    #pragma unroll
    for (int i = 0; i < 8; ++i) {
        int s = s0 + tm * 8 + i;
        float4 o = make_float4(acc[i][0] + c[0], acc[i][1] + c[1],
                               acc[i][2] + c[2], acc[i][3] + c[3]);
        *reinterpret_cast<float4*>(&scores[((size_t)b * SEQ + s) * BQ + tn * 4]) = o;
    }
}

// ---------------------------------------------------------------------------
// softmax over s (stride BQ) — 3 phases
// ---------------------------------------------------------------------------
__global__ __launch_bounds__(256)
void sm_partial(const float* __restrict__ scores, float* __restrict__ pmax,
                float* __restrict__ psum)
{
    const int b  = blockIdx.y;
    const int ch = blockIdx.x;      // 32 chunks of 128 rows
    const int t  = threadIdx.x;
    const int qi = t & 63;
    const int g  = t >> 6;          // 0..3
    const float* sb = scores + ((size_t)b * SEQ + ch * 128) * BQ;
    float v[32];
    #pragma unroll
    for (int i = 0; i < 32; ++i)
        v[i] = sb[(size_t)(g + i * 4) * BQ + qi];
    float m = v[0];
    #pragma unroll
    for (int i = 1; i < 32; ++i) m = fmaxf(m, v[i]);
    __shared__ float red[4][64];
    red[g][qi] = m;
    __syncthreads();
    float M = fmaxf(fmaxf(red[0][qi], red[1][qi]), fmaxf(red[2][qi], red[3][qi]));
    float sum = 0.f;
    #pragma unroll
    for (int i = 0; i < 32; ++i) sum += __expf(v[i] - M);
    __syncthreads();
    red[g][qi] = sum;
    __syncthreads();
    if (g == 0) {
        float ssum = red[0][qi] + red[1][qi] + red[2][qi] + red[3][qi];
        pmax[((size_t)b * 32 + ch) * 64 + qi] = M;
        psum[((size_t)b * 32 + ch) * 64 + qi] = ssum;
    }
}

__global__ void sm_combine(const float* __restrict__ pmax,
                           const float* __restrict__ psum,
                           float* __restrict__ gstat)
{
    int b  = blockIdx.x;
    int qi = threadIdx.x; // 64
    float m = -1e30f;
    for (int c = 0; c < 32; ++c)
        m = fmaxf(m, pmax[((size_t)b * 32 + c) * 64 + qi]);
    float s = 0.f;
    for (int c = 0; c < 32; ++c)
        s += psum[((size_t)b * 32 + c) * 64 + qi] *
             __expf(pmax[((size_t)b * 32 + c) * 64 + qi] - m);
    gstat[(size_t)b * 64 + qi] = m;
    gstat[(size_t)(NB + b) * 64 + qi] = 1.f / s;
}

__global__ __launch_bounds__(256)
void sm_norm(float* __restrict__ attn, const float* __restrict__ gstat,
             __hip_bfloat16* __restrict__ abf)
{
    const int b  = blockIdx.y;
    const int ch = blockIdx.x;
    const int t  = threadIdx.x;
    const int qi = t & 63;
    const int g  = t >> 6;
    const float M   = gstat[(size_t)b * 64 + qi];
    const float inv = gstat[(size_t)(NB + b) * 64 + qi];
    float* sb = attn + ((size_t)b * SEQ + ch * 128) * BQ;
    __hip_bfloat16* ab = abf + ((size_t)b * SEQ + ch * 128) * BQ;
    #pragma unroll 8
    for (int i = 0; i < 32; ++i) {
        size_t idx = (size_t)(g + i * 4) * BQ + qi;
        float w = __expf(sb[idx] - M) * inv;
        sb[idx] = w;
        ab[idx] = __float2bfloat16(w);
    }
}

// ---------------------------------------------------------------------------
// Tpart[half][b][qi][h] = sum_{s in half} attn_bf16[b,s,qi] * values[b,s,h]
// block: 64 qi x 128 h, grid (8, 2, B)
// ---------------------------------------------------------------------------
__global__ __launch_bounds__(256)
void tmat_kernel(const __hip_bfloat16* __restrict__ abf,
                 const float* __restrict__ values, float* __restrict__ Tpart)
{
    __shared__ float As[32][68];   // attn   [k(s)][qi]
    __shared__ float Bs[32][132];  // values [k][h], 128 h
    const int b    = blockIdx.z;
    const int half = blockIdx.y;
    const int h0   = blockIdx.x * 128;
    const int t    = threadIdx.x;
    const int tn   = t & 15;  // qi*4
    const int tm   = t >> 4;  // h*8
    const __hip_bfloat16* ab = abf + ((size_t)b * SEQ + half * 2048) * BQ;
    const float* vb = values + ((size_t)b * SEQ + half * 2048) * H;
    float acc[4][8] = {};

    for (int k0 = 0; k0 < 2048; k0 += 32) {
        {   // attn 32x64 bf16 -> As[k][qi] (f32)
            int qi = t & 63;
            int kb = t >> 6;
            #pragma unroll
            for (int p = 0; p < 8; ++p) {
                int kk = kb + p * 4;
                As[kk][qi] = __bfloat162float(ab[(size_t)(k0 + kk) * BQ + qi]);
            }
        }
        {   // values 32x128 -> Bs[k][h]
            int hf = t & 31;
            int kb = t >> 5;
            #pragma unroll
            for (int p = 0; p < 4; ++p) {
                int kk = kb + p * 8;
                float4 v = *reinterpret_cast<const float4*>(
                    &vb[(size_t)(k0 + kk) * H + h0 + hf * 4]);
                *reinterpret_cast<float4*>(&Bs[kk][hf * 4]) = v;
            }
        }
        __syncthreads();
        #pragma unroll 8
        for (int kk = 0; kk < 32; ++kk) {
            float4 a4 = *reinterpret_cast<const float4*>(&As[kk][tn * 4]);
            float v8[8];
            *reinterpret_cast<float4*>(&v8[0]) =
                *reinterpret_cast<const float4*>(&Bs[kk][tm * 8]);
            *reinterpret_cast<float4*>(&v8[4]) =
                *reinterpret_cast<const float4*>(&Bs[kk][tm * 8 + 4]);
            float av[4] = {a4.x, a4.y, a4.z, a4.w};
            #pragma unroll
            for (int j = 0; j < 4; ++j)
                #pragma unroll
                for (int i = 0; i < 8; ++i)
                    acc[j][i] += av[j] * v8[i];
        }
        __syncthreads();
    }

    float* Tb = Tpart + ((size_t)half * NB + b) * BQ * H;
    #pragma unroll
    for (int j = 0; j < 4; ++j) {
        int qi = tn * 4 + j;
        #pragma unroll
        for (int i = 0; i < 8; i += 4) {
            float4 o = make_float4(acc[j][i], acc[j][i + 1],
                                   acc[j][i + 2], acc[j][i + 3]);
            *reinterpret_cast<float4*>(&Tb[(size_t)qi * H + h0 + tm * 8 + i]) = o;
        }
    }
}

// ---------------------------------------------------------------------------
extern "C" void kernel_launch(void* const* d_in, const int* in_sizes, int n_in,
                              void* d_out, int out_size, void* d_ws, size_t ws_size,
                              hipStream_t stream)
{
    const float* queries = (const float*)d_in[0];
    const float* keys    = (const float*)d_in[1];
    const float* values  = (const float*)d_in[2];
    const float* Wq = (const float*)d_in[3];
    const float* bq = (const float*)d_in[4];
    const float* Wk = (const float*)d_in[5];
    const float* bk = (const float*)d_in[6];
    const float* Wv = (const float*)d_in[7];
    const float* bv = (const float*)d_in[8];

    float* out     = (float*)d_out;
    float* context = out;                          // 16*64*1024 f32
    float* attn    = out + (size_t)NB * BQ * H;    // 16*4096*64 f32 (also scores scratch)

    char* ws = (char*)d_ws;
    float* q     = (float*)(ws);                          // 4 MiB
    float* Nw    = (float*)(ws + (4u << 20));             // 4 MiB
    float* cvec  = (float*)(ws + (8u << 20));             // 4 KiB
    float* gstat = (float*)(ws + (8u << 20) + (64u << 10));  // 8 KiB
    float* pmax  = (float*)(ws + (8u << 20) + (128u << 10)); // 128 KiB
    float* psum  = (float*)(ws + (8u << 20) + (256u << 10)); // 128 KiB
    __hip_bfloat16* abf = (__hip_bfloat16*)(ws + (9u << 20)); // 8 MiB
    float* Tpart = (float*)(ws + (17u << 20));            // 8 MiB (2 halves)

    const float scale = 0.03125f; // 1/sqrt(1024)

    // q = queries @ Wq^T + bq
    gemm_small<true, false><<<dim3(16, 16), 256, 0, stream>>>(
        queries, nullptr, Wq, bq, q, 1.0f);
    // N = (q @ Wk) * scale
    gemm_small<false, false><<<dim3(16, 16), 256, 0, stream>>>(
        q, nullptr, Wk, nullptr, Nw, scale);
    // c = (q . bk) * scale
    cvec_kernel<<<256, 256, 0, stream>>>(q, bk, cvec, scale);
    // scores -> attn region of d_out
    scores_kernel<<<dim3(32, 16), 256, 0, stream>>>(keys, Nw, cvec, attn);
    // softmax over s
    sm_partial<<<dim3(32, 16), 256, 0, stream>>>(attn, pmax, psum);
    sm_combine<<<16, 64, 0, stream>>>(pmax, psum, gstat);
    sm_norm<<<dim3(32, 16), 256, 0, stream>>>(attn, gstat, abf);
    // T = attn^T @ values (split-K over 2 halves)
    tmat_kernel<<<dim3(8, 2, 16), 256, 0, stream>>>(abf, values, Tpart);
    // context = (T0+T1) @ Wv^T + bv
    gemm_small<true, true><<<dim3(16, 16), 256, 0, stream>>>(
        Tpart, Tpart + ((size_t)4 << 20) / 4, Wv, bv, context, 1.0f);
}